// Round 11
// baseline (364.245 us; speedup 1.0000x reference)
//
#include <hip/hip_runtime.h>

#define N_NODES 102
#define NP 8192          // pairs (B*n)
#define NPAIR_STAGE 12   // max pairs a 1024-row block can span: floor((101+1023)/102)+1

typedef _Float16 f16x8 __attribute__((ext_vector_type(8)));
typedef _Float16 f16x2 __attribute__((ext_vector_type(2)));
typedef float f32x4 __attribute__((ext_vector_type(4)));

#define LDW 264  // padded LDS row stride in f16 elems (proven best in R3)

// ---------------- Kernel 1: build sparse propagation tables ----------------------
__global__ void build_tables(const int* __restrict__ ei, int ne,
                             int4* __restrict__ gtu, float4* __restrict__ gtw) {
    __shared__ int   deg[N_NODES];
    __shared__ float dinv[N_NODES];
    __shared__ int   cnt[N_NODES];
    __shared__ int   tu[N_NODES][4];
    __shared__ float tw[N_NODES][4];
    int t = threadIdx.x;
    if (t < N_NODES) deg[t] = 1;                       // self-loop
    __syncthreads();
    if (t == 0) for (int e = 0; e < ne; ++e) deg[ei[ne + e]] += 1;
    __syncthreads();
    if (t < N_NODES) {
        dinv[t] = 1.0f / sqrtf((float)deg[t]);
        cnt[t] = 1;
        for (int j = 0; j < 4; ++j) { tu[t][j] = 2 * t; tw[t][j] = 0.0f; }
    }
    __syncthreads();
    if (t < N_NODES) tw[t][0] = dinv[t] * dinv[t];     // diagonal self-loop
    __syncthreads();
    if (t == 0) {
        for (int e = 0; e < ne; ++e) {
            int r = ei[e], c = ei[ne + e];
            int s = cnt[c] < 4 ? cnt[c] : 3;           // clamp (never hit here)
            cnt[c] = s + 1;
            tu[c][s] = 2 * r;
            tw[c][s] = dinv[r] * dinv[c];
        }
    }
    __syncthreads();
    if (t < N_NODES) {
        gtu[t] = make_int4(tu[t][0], tu[t][1], tu[t][2], tu[t][3]);
        gtw[t] = make_float4(tw[t][0], tw[t][1], tw[t][2], tw[t][3]);
    }
}

// ---------------- Kernel 2: fused y + out = relu(y0*W0+y1*W1+b) @ Wp + bp --------
// R9 structure + 1024 rows/block in 4 phases of 256 — Wl/xs/tables staged ONCE.
// (R10 bug fixed: stage 12 pairs, not 11.)
__global__ __launch_bounds__(256, 2) void gnn_main(
    const float* __restrict__ x,     // [NP][204] fp32
    const int4*  __restrict__ gtu,   // [102] premult-by-2 src indices
    const float4* __restrict__ gtw,  // [102] weights
    const float* __restrict__ Wg,    // [2][256]
    const float* __restrict__ bg,    // [256]
    const float* __restrict__ Wp,    // [256][256] (k-major)
    const float* __restrict__ bp,    // [256]
    float* __restrict__ out)         // [R][256]
{
    __shared__ _Float16 Wl[64 * LDW];                  // 33.8 KB
    __shared__ float xs[NPAIR_STAGE * 2 * N_NODES];    // 9.8 KB: 12 pairs of x
    __shared__ int4   stu[N_NODES];                    // 1.6 KB
    __shared__ float4 stw[N_NODES];                    // 1.6 KB
    const int tid = threadIdx.x;
    const int c0 = blockIdx.y * 64;

    const int rowblk = blockIdx.x * 1024;
    const int pbase  = rowblk / N_NODES;

    // Stage W_proj[:, c0:c0+64] transposed -> Wl[cc][k] as f16 (R3-verbatim)
    {
        int cc = tid & 63;
        int ks = tid >> 6;
        for (int k = ks; k < 256; k += 4) {
            Wl[cc * LDW + k] = (_Float16)Wp[k * 256 + c0 + cc];
        }
    }
    // Stage x for the <=12 pairs this block spans (flat, coalesced)
    {
        const int nx = NPAIR_STAGE * 2 * N_NODES;        // 2448
        const size_t gbase = (size_t)pbase * (2 * N_NODES);
        const size_t gmax  = (size_t)NP * (2 * N_NODES);
        for (int i = tid; i < nx; i += 256)
            xs[i] = (gbase + i < gmax) ? x[gbase + i] : 0.0f;
    }
    // Stage sparse tables
    if (tid < N_NODES) { stu[tid] = gtu[tid]; stw[tid] = gtw[tid]; }
    __syncthreads();

    const int w  = tid >> 6;   // wave 0..3
    const int l  = tid & 63;   // lane
    const int qk = l >> 4;     // k-quarter 0..3
    const int m  = l & 15;

    // Per-lane slices of W0/W1/b as packed f16x2 (R9-verbatim)
    f16x2 w0pk[8][4], w1pk[8][4], bpk[8][4];
    #pragma unroll
    for (int t = 0; t < 8; ++t) {
        int k0 = qk * 8 + 32 * t;
        #pragma unroll
        for (int j2 = 0; j2 < 4; ++j2) {
            w0pk[t][j2] = (f16x2){ (_Float16)Wg[k0 + 2 * j2],
                                   (_Float16)Wg[k0 + 2 * j2 + 1] };
            w1pk[t][j2] = (f16x2){ (_Float16)Wg[256 + k0 + 2 * j2],
                                   (_Float16)Wg[256 + k0 + 2 * j2 + 1] };
            bpk[t][j2]  = (f16x2){ (_Float16)bg[k0 + 2 * j2],
                                   (_Float16)bg[k0 + 2 * j2 + 1] };
        }
    }

    // Epilogue bias (hoisted; invariant across phases)
    float bpf[4];
    #pragma unroll
    for (int nt = 0; nt < 4; ++nt) bpf[nt] = bp[c0 + nt * 16 + m];

    const f16x2 z2 = (f16x2){ (_Float16)0.0f, (_Float16)0.0f };

    #pragma unroll 1
    for (int ph = 0; ph < 4; ++ph) {
        const long rowbase = (long)rowblk + ph * 256 + (long)w * 64;

        // y per row-stripe from sparse tables (xs in LDS)
        f16x2 y0pk[4], y1pk[4];
        #pragma unroll
        for (int s = 0; s < 4; ++s) {
            int r = rowblk + ph * 256 + w * 64 + s * 16 + m;
            int p = r / N_NODES;                  // magic-mul division
            int v = r - p * N_NODES;
            const float* xp = &xs[(p - pbase) * 2 * N_NODES];
            int4  U = stu[v];
            float4 W = stw[v];
            float a0 = W.x * xp[U.x]     + W.y * xp[U.y]
                     + W.z * xp[U.z]     + W.w * xp[U.w];
            float a1 = W.x * xp[U.x + 1] + W.y * xp[U.y + 1]
                     + W.z * xp[U.z + 1] + W.w * xp[U.w + 1];
            _Float16 h0 = (_Float16)a0;
            _Float16 h1 = (_Float16)a1;
            y0pk[s] = (f16x2){ h0, h0 };
            y1pk[s] = (f16x2){ h1, h1 };
        }

        f32x4 acc[4][4];
        #pragma unroll
        for (int s = 0; s < 4; ++s)
            #pragma unroll
            for (int nt = 0; nt < 4; ++nt)
                acc[s][nt] = (f32x4){0.f, 0.f, 0.f, 0.f};

        #pragma unroll
        for (int t = 0; t < 8; ++t) {
            const int kk = qk * 8 + 32 * t;
            f16x8 bfrag[4];
            #pragma unroll
            for (int nt = 0; nt < 4; ++nt)
                bfrag[nt] = *reinterpret_cast<const f16x8*>(&Wl[(nt * 16 + m) * LDW + kk]);
            #pragma unroll
            for (int s = 0; s < 4; ++s) {
                union { f16x8 v; f16x2 p[4]; } af;
                #pragma unroll
                for (int j2 = 0; j2 < 4; ++j2) {
                    f16x2 h = w0pk[t][j2] * y0pk[s] + w1pk[t][j2] * y1pk[s] + bpk[t][j2];
                    af.p[j2] = __builtin_elementwise_max(h, z2);
                }
                #pragma unroll
                for (int nt = 0; nt < 4; ++nt)
                    acc[s][nt] = __builtin_amdgcn_mfma_f32_16x16x32_f16(af.v, bfrag[nt], acc[s][nt], 0, 0, 0);
            }
        }

        // Epilogue: + b_proj, store fp32 (R9-verbatim)
        #pragma unroll
        for (int s = 0; s < 4; ++s) {
            #pragma unroll
            for (int nt = 0; nt < 4; ++nt) {
                const int e = c0 + nt * 16 + m;
                #pragma unroll
                for (int reg = 0; reg < 4; ++reg) {
                    long r = rowbase + s * 16 + qk * 4 + reg;
                    out[r * 256 + e] = acc[s][nt][reg] + bpf[nt];
                }
            }
        }
    }
}

extern "C" void kernel_launch(void* const* d_in, const int* in_sizes, int n_in,
                              void* d_out, int out_size, void* d_ws, size_t ws_size,
                              hipStream_t stream) {
    const float* x  = (const float*)d_in[0];
    const float* Wg = (const float*)d_in[1];
    const float* bg = (const float*)d_in[2];
    const float* Wp = (const float*)d_in[3];
    const float* bp = (const float*)d_in[4];
    const int* ei   = (const int*)d_in[5];
    float* out = (float*)d_out;

    const int ne    = in_sizes[5] / 2;              // 84
    const int pairs = in_sizes[0] / (N_NODES * 2);  // 8192
    const int rows  = pairs * N_NODES;              // 835584

    int4*   gtu = (int4*)d_ws;                      // 102 int4
    float4* gtw = (float4*)((char*)d_ws + 2048);    // 102 float4

    build_tables<<<1, 128, 0, stream>>>(ei, ne, gtu, gtw);

    const int rowblocks = rows / 1024;              // 816
    gnn_main<<<dim3(rowblocks, 4), 256, 0, stream>>>(x, gtu, gtw, Wg, bg, Wp, bp, out);
}

// Round 12
// 329.432 us; speedup vs baseline: 1.1057x; 1.1057x over previous
//
#include <hip/hip_runtime.h>

#define N_NODES 102
#define NP 8192          // pairs (B*n)

typedef _Float16 f16x8 __attribute__((ext_vector_type(8)));
typedef _Float16 f16x2 __attribute__((ext_vector_type(2)));
typedef float f32x4 __attribute__((ext_vector_type(4)));

#define LDW 264  // padded LDS row stride in f16 elems (proven best in R3)

// ---------------- Kernel 1: build sparse propagation tables ----------------------
__global__ void build_tables(const int* __restrict__ ei, int ne,
                             int4* __restrict__ gtu, float4* __restrict__ gtw) {
    __shared__ int   deg[N_NODES];
    __shared__ float dinv[N_NODES];
    __shared__ int   cnt[N_NODES];
    __shared__ int   tu[N_NODES][4];
    __shared__ float tw[N_NODES][4];
    int t = threadIdx.x;
    if (t < N_NODES) deg[t] = 1;                       // self-loop
    __syncthreads();
    if (t == 0) for (int e = 0; e < ne; ++e) deg[ei[ne + e]] += 1;
    __syncthreads();
    if (t < N_NODES) {
        dinv[t] = 1.0f / sqrtf((float)deg[t]);
        cnt[t] = 1;
        for (int j = 0; j < 4; ++j) { tu[t][j] = 2 * t; tw[t][j] = 0.0f; }
    }
    __syncthreads();
    if (t < N_NODES) tw[t][0] = dinv[t] * dinv[t];     // diagonal self-loop
    __syncthreads();
    if (t == 0) {
        for (int e = 0; e < ne; ++e) {
            int r = ei[e], c = ei[ne + e];
            int s = cnt[c] < 4 ? cnt[c] : 3;           // clamp (never hit here)
            cnt[c] = s + 1;
            tu[c][s] = 2 * r;
            tw[c][s] = dinv[r] * dinv[c];
        }
    }
    __syncthreads();
    if (t < N_NODES) {
        gtu[t] = make_int4(tu[t][0], tu[t][1], tu[t][2], tu[t][3]);
        gtw[t] = make_float4(tw[t][0], tw[t][1], tw[t][2], tw[t][3]);
    }
}

// ---------------- Kernel 2: fused y + out = relu(y0*W0+y1*W1+b) @ Wp + bp --------
// R9-verbatim EXCEPT: mfma operand order swapped (A=Wp frag, B=h frag) and the
// epilogue stores float4 (each lane's 4 acc regs = 4 consecutive out-cols).
// All LDS reads, VALU work, and register pressure identical to R9 — isolates
// the store-path variable.
__global__ __launch_bounds__(256, 2) void gnn_main(
    const float* __restrict__ x,     // [NP][204] fp32
    const int4*  __restrict__ gtu,   // [102] premult-by-2 src indices
    const float4* __restrict__ gtw,  // [102] weights
    const float* __restrict__ Wg,    // [2][256]
    const float* __restrict__ bg,    // [256]
    const float* __restrict__ Wp,    // [256][256] (k-major)
    const float* __restrict__ bp,    // [256]
    float* __restrict__ out)         // [R][256]
{
    __shared__ _Float16 Wl[64 * LDW];       // 33.8 KB
    __shared__ float xs[4 * 2 * N_NODES];   // 3.3 KB: 4 pairs of x
    __shared__ int4  stu[N_NODES];          // 1.6 KB
    __shared__ float4 stw[N_NODES];         // 1.6 KB
    const int tid = threadIdx.x;
    const int c0 = blockIdx.y * 64;

    const int rowblk = blockIdx.x * 256;
    const int pbase  = rowblk / N_NODES;

    // Stage W_proj[:, c0:c0+64] transposed -> Wl[cc][k] as f16 (R3-verbatim)
    {
        int cc = tid & 63;
        int ks = tid >> 6;
        for (int k = ks; k < 256; k += 4) {
            Wl[cc * LDW + k] = (_Float16)Wp[k * 256 + c0 + cc];
        }
    }
    // Stage x for the <=4 pairs this block spans (coalesced)
    #pragma unroll
    for (int pi = 0; pi < 4; ++pi) {
        int p = pbase + pi;
        if (tid < 2 * N_NODES)
            xs[pi * 2 * N_NODES + tid] = (p < NP) ? x[(size_t)p * (2 * N_NODES) + tid] : 0.0f;
    }
    // Stage sparse tables
    if (tid < N_NODES) { stu[tid] = gtu[tid]; stw[tid] = gtw[tid]; }
    __syncthreads();

    const int w  = tid >> 6;   // wave 0..3
    const int l  = tid & 63;   // lane
    const int qk = l >> 4;     // k-quarter 0..3
    const int m  = l & 15;

    // Per-lane slices of W0/W1/b as packed f16x2 (R9-verbatim)
    f16x2 w0pk[8][4], w1pk[8][4], bpk[8][4];
    #pragma unroll
    for (int t = 0; t < 8; ++t) {
        int k0 = qk * 8 + 32 * t;
        #pragma unroll
        for (int j2 = 0; j2 < 4; ++j2) {
            w0pk[t][j2] = (f16x2){ (_Float16)Wg[k0 + 2 * j2],
                                   (_Float16)Wg[k0 + 2 * j2 + 1] };
            w1pk[t][j2] = (f16x2){ (_Float16)Wg[256 + k0 + 2 * j2],
                                   (_Float16)Wg[256 + k0 + 2 * j2 + 1] };
            bpk[t][j2]  = (f16x2){ (_Float16)bg[k0 + 2 * j2],
                                   (_Float16)bg[k0 + 2 * j2 + 1] };
        }
    }

    const long rowbase = (long)rowblk + (long)w * 64;

    // y per row-stripe from sparse tables (xs in LDS) — row = lane&15 (B-col)
    f16x2 y0pk[4], y1pk[4];
    #pragma unroll
    for (int s = 0; s < 4; ++s) {
        int r = rowblk + w * 64 + s * 16 + m;
        int p = r / N_NODES;                  // magic-mul division
        int v = r - p * N_NODES;
        const float* xp = &xs[(p - pbase) * 2 * N_NODES];
        int4  U = stu[v];
        float4 W = stw[v];
        float a0 = W.x * xp[U.x]     + W.y * xp[U.y]
                 + W.z * xp[U.z]     + W.w * xp[U.w];
        float a1 = W.x * xp[U.x + 1] + W.y * xp[U.y + 1]
                 + W.z * xp[U.z + 1] + W.w * xp[U.w + 1];
        _Float16 h0 = (_Float16)a0;
        _Float16 h1 = (_Float16)a1;
        y0pk[s] = (f16x2){ h0, h0 };
        y1pk[s] = (f16x2){ h1, h1 };
    }

    f32x4 acc[4][4];
    #pragma unroll
    for (int s = 0; s < 4; ++s)
        #pragma unroll
        for (int nt = 0; nt < 4; ++nt)
            acc[s][nt] = (f32x4){0.f, 0.f, 0.f, 0.f};

    const f16x2 z2 = (f16x2){ (_Float16)0.0f, (_Float16)0.0f };

    #pragma unroll
    for (int t = 0; t < 8; ++t) {
        const int kk = qk * 8 + 32 * t;
        f16x8 bfrag[4];
        #pragma unroll
        for (int nt = 0; nt < 4; ++nt)
            bfrag[nt] = *reinterpret_cast<const f16x8*>(&Wl[(nt * 16 + m) * LDW + kk]);
        #pragma unroll
        for (int s = 0; s < 4; ++s) {
            union { f16x8 v; f16x2 p[4]; } af;
            #pragma unroll
            for (int j2 = 0; j2 < 4; ++j2) {
                f16x2 h = w0pk[t][j2] * y0pk[s] + w1pk[t][j2] * y1pk[s] + bpk[t][j2];
                af.p[j2] = __builtin_elementwise_max(h, z2);
            }
            // SWAPPED vs R9: A = Wp fragment, B = h fragment
            #pragma unroll
            for (int nt = 0; nt < 4; ++nt)
                acc[s][nt] = __builtin_amdgcn_mfma_f32_16x16x32_f16(bfrag[nt], af.v, acc[s][nt], 0, 0, 0);
        }
    }

    // Epilogue: + b_proj, float4 stores (lane's 4 regs = 4 consecutive out-cols)
    f32x4 bp4[4];
    #pragma unroll
    for (int nt = 0; nt < 4; ++nt)
        bp4[nt] = *reinterpret_cast<const f32x4*>(&bp[c0 + nt * 16 + qk * 4]);
    #pragma unroll
    for (int s = 0; s < 4; ++s) {
        float* rowp = out + (rowbase + s * 16 + m) * 256 + c0 + (qk << 2);
        #pragma unroll
        for (int nt = 0; nt < 4; ++nt) {
            f32x4 v = acc[s][nt] + bp4[nt];
            *reinterpret_cast<f32x4*>(rowp + nt * 16) = v;
        }
    }
}

extern "C" void kernel_launch(void* const* d_in, const int* in_sizes, int n_in,
                              void* d_out, int out_size, void* d_ws, size_t ws_size,
                              hipStream_t stream) {
    const float* x  = (const float*)d_in[0];
    const float* Wg = (const float*)d_in[1];
    const float* bg = (const float*)d_in[2];
    const float* Wp = (const float*)d_in[3];
    const float* bp = (const float*)d_in[4];
    const int* ei   = (const int*)d_in[5];
    float* out = (float*)d_out;

    const int ne    = in_sizes[5] / 2;              // 84
    const int pairs = in_sizes[0] / (N_NODES * 2);  // 8192
    const int rows  = pairs * N_NODES;              // 835584

    int4*   gtu = (int4*)d_ws;                      // 102 int4
    float4* gtw = (float4*)((char*)d_ws + 2048);    // 102 float4

    build_tables<<<1, 128, 0, stream>>>(ei, ne, gtu, gtw);

    const int rowblocks = rows / 256;               // 3264
    gnn_main<<<dim3(rowblocks, 4), 256, 0, stream>>>(x, gtu, gtw, Wg, bg, Wp, bp, out);
}

// Round 13
// 322.919 us; speedup vs baseline: 1.1280x; 1.0202x over previous
//
#include <hip/hip_runtime.h>

#define N_NODES 102
#define NP 8192          // pairs (B*n)

typedef _Float16 f16x8 __attribute__((ext_vector_type(8)));
typedef _Float16 f16x2 __attribute__((ext_vector_type(2)));
typedef float f32x4 __attribute__((ext_vector_type(4)));

// ---------------- Kernel 1: build sparse propagation tables ----------------------
__global__ void build_tables(const int* __restrict__ ei, int ne,
                             int4* __restrict__ gtu, float4* __restrict__ gtw) {
    __shared__ int   deg[N_NODES];
    __shared__ float dinv[N_NODES];
    __shared__ int   cnt[N_NODES];
    __shared__ int   tu[N_NODES][4];
    __shared__ float tw[N_NODES][4];
    int t = threadIdx.x;
    if (t < N_NODES) deg[t] = 1;                       // self-loop
    __syncthreads();
    if (t == 0) for (int e = 0; e < ne; ++e) deg[ei[ne + e]] += 1;
    __syncthreads();
    if (t < N_NODES) {
        dinv[t] = 1.0f / sqrtf((float)deg[t]);
        cnt[t] = 1;
        for (int j = 0; j < 4; ++j) { tu[t][j] = 2 * t; tw[t][j] = 0.0f; }
    }
    __syncthreads();
    if (t < N_NODES) tw[t][0] = dinv[t] * dinv[t];     // diagonal self-loop
    __syncthreads();
    if (t == 0) {
        for (int e = 0; e < ne; ++e) {
            int r = ei[e], c = ei[ne + e];
            int s = cnt[c] < 4 ? cnt[c] : 3;           // clamp (never hit here)
            cnt[c] = s + 1;
            tu[c][s] = 2 * r;
            tw[c][s] = dinv[r] * dinv[c];
        }
    }
    __syncthreads();
    if (t < N_NODES) {
        gtu[t] = make_int4(tu[t][0], tu[t][1], tu[t][2], tu[t][3]);
        gtw[t] = make_float4(tw[t][0], tw[t][1], tw[t][2], tw[t][3]);
    }
}

// ---------------- Kernel 1b: WpT[col][k] = (f16)Wp[k][col] — one-time transpose --
__global__ void prep_w(const float* __restrict__ Wp, _Float16* __restrict__ WpT) {
    int tid = blockIdx.x * 256 + threadIdx.x;          // 64 x 256 = 16384
    for (int i = tid; i < 65536; i += 16384) {         // i = k*256 + col (coalesced read)
        int col = i & 255, k = i >> 8;
        WpT[col * 256 + k] = (_Float16)Wp[i];
    }
}

// ---------------- Kernel 2: fused y + out = relu(y0*W0+y1*W1+b) @ Wp + bp --------
// R9 structure with Wp staging DELETED: B-fragments read straight from L2-resident
// pre-transposed WpT (16B contiguous per lane). No ds_write staging, no big LDS,
// no stage barrier -> waves free-run, stores stream. Wg weights via LDS (frees
// ~96 VGPRs) -> 3 blocks/CU. Proven R9 elements kept: mfma(af,bfrag) orientation,
// scalar-store epilogue, 256-row blocks, fused sparse y.
__global__ __launch_bounds__(256, 3) void gnn_main(
    const float* __restrict__ x,       // [NP][204] fp32
    const _Float16* __restrict__ WpT,  // [256 col][256 k] f16
    const int4*  __restrict__ gtu,     // [102]
    const float4* __restrict__ gtw,    // [102]
    const float* __restrict__ Wg,      // [2][256]
    const float* __restrict__ bg,      // [256]
    const float* __restrict__ bp,      // [256]
    float* __restrict__ out)           // [R][256]
{
    __shared__ float xs[4 * 2 * N_NODES];   // 3.3 KB
    __shared__ int4   stu[N_NODES];         // 1.6 KB
    __shared__ float4 stw[N_NODES];         // 1.6 KB
    __shared__ _Float16 W0l[256], W1l[256], bgl[256];  // 1.5 KB
    const int tid = threadIdx.x;
    const int c0 = blockIdx.y * 64;

    const int rowblk = blockIdx.x * 256;
    const int pbase  = rowblk / N_NODES;

    // Stage x for the <=4 pairs this block spans (coalesced)
    #pragma unroll
    for (int pi = 0; pi < 4; ++pi) {
        int p = pbase + pi;
        if (tid < 2 * N_NODES)
            xs[pi * 2 * N_NODES + tid] = (p < NP) ? x[(size_t)p * (2 * N_NODES) + tid] : 0.0f;
    }
    if (tid < N_NODES) { stu[tid] = gtu[tid]; stw[tid] = gtw[tid]; }
    W0l[tid] = (_Float16)Wg[tid];
    W1l[tid] = (_Float16)Wg[256 + tid];
    bgl[tid] = (_Float16)bg[tid];
    __syncthreads();

    const int w  = tid >> 6;   // wave 0..3
    const int l  = tid & 63;   // lane
    const int qk = l >> 4;     // k-quarter 0..3
    const int m  = l & 15;

    const long rowbase = (long)rowblk + (long)w * 64;

    // y per row-stripe from sparse tables (R9-verbatim)
    f16x2 y0pk[4], y1pk[4];
    #pragma unroll
    for (int s = 0; s < 4; ++s) {
        int r = rowblk + w * 64 + s * 16 + m;
        int p = r / N_NODES;
        int v = r - p * N_NODES;
        const float* xp = &xs[(p - pbase) * 2 * N_NODES];
        int4  U = stu[v];
        float4 W = stw[v];
        float a0 = W.x * xp[U.x]     + W.y * xp[U.y]
                 + W.z * xp[U.z]     + W.w * xp[U.w];
        float a1 = W.x * xp[U.x + 1] + W.y * xp[U.y + 1]
                 + W.z * xp[U.z + 1] + W.w * xp[U.w + 1];
        _Float16 h0 = (_Float16)a0;
        _Float16 h1 = (_Float16)a1;
        y0pk[s] = (f16x2){ h0, h0 };
        y1pk[s] = (f16x2){ h1, h1 };
    }

    f32x4 acc[4][4];
    #pragma unroll
    for (int s = 0; s < 4; ++s)
        #pragma unroll
        for (int nt = 0; nt < 4; ++nt)
            acc[s][nt] = (f32x4){0.f, 0.f, 0.f, 0.f};

    const f16x2 z2 = (f16x2){ (_Float16)0.0f, (_Float16)0.0f };

    #pragma unroll
    for (int t = 0; t < 8; ++t) {
        const int kk = qk * 8 + 32 * t;
        // B-fragments straight from L2-resident WpT: 16B contiguous per lane
        f16x8 bfrag[4];
        #pragma unroll
        for (int nt = 0; nt < 4; ++nt)
            bfrag[nt] = *reinterpret_cast<const f16x8*>(&WpT[(c0 + nt * 16 + m) * 256 + kk]);
        // Wg slices from LDS
        union { f16x8 v; f16x2 p[4]; } w0u, w1u, bbu;
        w0u.v = *reinterpret_cast<const f16x8*>(&W0l[kk]);
        w1u.v = *reinterpret_cast<const f16x8*>(&W1l[kk]);
        bbu.v = *reinterpret_cast<const f16x8*>(&bgl[kk]);
        #pragma unroll
        for (int s = 0; s < 4; ++s) {
            union { f16x8 v; f16x2 p[4]; } af;
            #pragma unroll
            for (int j2 = 0; j2 < 4; ++j2) {
                f16x2 h = w0u.p[j2] * y0pk[s] + w1u.p[j2] * y1pk[s] + bbu.p[j2];
                af.p[j2] = __builtin_elementwise_max(h, z2);
            }
            #pragma unroll
            for (int nt = 0; nt < 4; ++nt)
                acc[s][nt] = __builtin_amdgcn_mfma_f32_16x16x32_f16(af.v, bfrag[nt], acc[s][nt], 0, 0, 0);
        }
    }

    // Epilogue: + b_proj, scalar stores (R9-verbatim — proven best)
    float bpf[4];
    #pragma unroll
    for (int nt = 0; nt < 4; ++nt) bpf[nt] = bp[c0 + nt * 16 + m];
    #pragma unroll
    for (int s = 0; s < 4; ++s) {
        #pragma unroll
        for (int nt = 0; nt < 4; ++nt) {
            const int e = c0 + nt * 16 + m;
            #pragma unroll
            for (int reg = 0; reg < 4; ++reg) {
                long r = rowbase + s * 16 + qk * 4 + reg;
                out[r * 256 + e] = acc[s][nt][reg] + bpf[nt];
            }
        }
    }
}

extern "C" void kernel_launch(void* const* d_in, const int* in_sizes, int n_in,
                              void* d_out, int out_size, void* d_ws, size_t ws_size,
                              hipStream_t stream) {
    const float* x  = (const float*)d_in[0];
    const float* Wg = (const float*)d_in[1];
    const float* bg = (const float*)d_in[2];
    const float* Wp = (const float*)d_in[3];
    const float* bp = (const float*)d_in[4];
    const int* ei   = (const int*)d_in[5];
    float* out = (float*)d_out;

    const int ne    = in_sizes[5] / 2;              // 84
    const int pairs = in_sizes[0] / (N_NODES * 2);  // 8192
    const int rows  = pairs * N_NODES;              // 835584

    int4*     gtu = (int4*)d_ws;                        // 102 int4
    float4*   gtw = (float4*)((char*)d_ws + 2048);      // 102 float4
    _Float16* WpT = (_Float16*)((char*)d_ws + 4096);    // 65536 f16 = 128 KB

    build_tables<<<1, 128, 0, stream>>>(ei, ne, gtu, gtw);
    prep_w<<<64, 256, 0, stream>>>(Wp, WpT);

    const int rowblocks = rows / 256;               // 3264
    gnn_main<<<dim3(rowblocks, 4), 256, 0, stream>>>(x, WpT, gtu, gtw, Wg, bg, bp, out);
}

// Round 14
// 289.576 us; speedup vs baseline: 1.2579x; 1.1151x over previous
//
#include <hip/hip_runtime.h>

#define N_NODES 102
#define NP 8192          // pairs (B*n)

typedef _Float16 f16x8 __attribute__((ext_vector_type(8)));
typedef _Float16 f16x2 __attribute__((ext_vector_type(2)));
typedef float f32x4 __attribute__((ext_vector_type(4)));

#define LDW 264  // padded LDS row stride in f16 elems (proven best in R3)

// ---------------- Kernel 1: build sparse propagation tables ----------------------
__global__ void build_tables(const int* __restrict__ ei, int ne,
                             int4* __restrict__ gtu, float4* __restrict__ gtw) {
    __shared__ int   deg[N_NODES];
    __shared__ float dinv[N_NODES];
    __shared__ int   cnt[N_NODES];
    __shared__ int   tu[N_NODES][4];
    __shared__ float tw[N_NODES][4];
    int t = threadIdx.x;
    if (t < N_NODES) deg[t] = 1;                       // self-loop
    __syncthreads();
    if (t == 0) for (int e = 0; e < ne; ++e) deg[ei[ne + e]] += 1;
    __syncthreads();
    if (t < N_NODES) {
        dinv[t] = 1.0f / sqrtf((float)deg[t]);
        cnt[t] = 1;
        for (int j = 0; j < 4; ++j) { tu[t][j] = 2 * t; tw[t][j] = 0.0f; }
    }
    __syncthreads();
    if (t < N_NODES) tw[t][0] = dinv[t] * dinv[t];     // diagonal self-loop
    __syncthreads();
    if (t == 0) {
        for (int e = 0; e < ne; ++e) {
            int r = ei[e], c = ei[ne + e];
            int s = cnt[c] < 4 ? cnt[c] : 3;           // clamp (never hit here)
            cnt[c] = s + 1;
            tu[c][s] = 2 * r;
            tw[c][s] = dinv[r] * dinv[c];
        }
    }
    __syncthreads();
    if (t < N_NODES) {
        gtu[t] = make_int4(tu[t][0], tu[t][1], tu[t][2], tu[t][3]);
        gtw[t] = make_float4(tw[t][0], tw[t][1], tw[t][2], tw[t][3]);
    }
}

// ---------------- Kernel 2: fused y + out = relu(y0*W0+y1*W1+b) @ Wp + bp --------
// R9-verbatim EXCEPT: Wg/bg weight slices live in LDS instead of 96 VGPRs
// (3 extra conflict-free ds_read_b128 per t-iter), and launch_bounds(256,3).
// VGPR ~220 -> ~140, occupancy 2 -> 3 blocks/CU (+50% latency hiding).
__global__ __launch_bounds__(256, 3) void gnn_main(
    const float* __restrict__ x,     // [NP][204] fp32
    const int4*  __restrict__ gtu,   // [102] premult-by-2 src indices
    const float4* __restrict__ gtw,  // [102] weights
    const float* __restrict__ Wg,    // [2][256]
    const float* __restrict__ bg,    // [256]
    const float* __restrict__ Wp,    // [256][256] (k-major)
    const float* __restrict__ bp,    // [256]
    float* __restrict__ out)         // [R][256]
{
    __shared__ _Float16 Wl[64 * LDW];       // 33.8 KB
    __shared__ float xs[4 * 2 * N_NODES];   // 3.3 KB: 4 pairs of x
    __shared__ int4   stu[N_NODES];         // 1.6 KB
    __shared__ float4 stw[N_NODES];         // 1.6 KB
    __shared__ _Float16 W0l[256], W1l[256], bgl[256];  // 1.5 KB
    const int tid = threadIdx.x;
    const int c0 = blockIdx.y * 64;

    const int rowblk = blockIdx.x * 256;
    const int pbase  = rowblk / N_NODES;

    // Stage W_proj[:, c0:c0+64] transposed -> Wl[cc][k] as f16 (R3-verbatim)
    {
        int cc = tid & 63;
        int ks = tid >> 6;
        for (int k = ks; k < 256; k += 4) {
            Wl[cc * LDW + k] = (_Float16)Wp[k * 256 + c0 + cc];
        }
    }
    // Stage x for the <=4 pairs this block spans (coalesced)
    #pragma unroll
    for (int pi = 0; pi < 4; ++pi) {
        int p = pbase + pi;
        if (tid < 2 * N_NODES)
            xs[pi * 2 * N_NODES + tid] = (p < NP) ? x[(size_t)p * (2 * N_NODES) + tid] : 0.0f;
    }
    // Stage sparse tables + GNN weights (f16)
    if (tid < N_NODES) { stu[tid] = gtu[tid]; stw[tid] = gtw[tid]; }
    W0l[tid] = (_Float16)Wg[tid];
    W1l[tid] = (_Float16)Wg[256 + tid];
    bgl[tid] = (_Float16)bg[tid];
    __syncthreads();

    const int w  = tid >> 6;   // wave 0..3
    const int l  = tid & 63;   // lane
    const int qk = l >> 4;     // k-quarter 0..3
    const int m  = l & 15;

    const long rowbase = (long)rowblk + (long)w * 64;

    // y per row-stripe from sparse tables (R9-verbatim)
    f16x2 y0pk[4], y1pk[4];
    #pragma unroll
    for (int s = 0; s < 4; ++s) {
        int r = rowblk + w * 64 + s * 16 + m;
        int p = r / N_NODES;                  // magic-mul division
        int v = r - p * N_NODES;
        const float* xp = &xs[(p - pbase) * 2 * N_NODES];
        int4  U = stu[v];
        float4 W = stw[v];
        float a0 = W.x * xp[U.x]     + W.y * xp[U.y]
                 + W.z * xp[U.z]     + W.w * xp[U.w];
        float a1 = W.x * xp[U.x + 1] + W.y * xp[U.y + 1]
                 + W.z * xp[U.z + 1] + W.w * xp[U.w + 1];
        _Float16 h0 = (_Float16)a0;
        _Float16 h1 = (_Float16)a1;
        y0pk[s] = (f16x2){ h0, h0 };
        y1pk[s] = (f16x2){ h1, h1 };
    }

    f32x4 acc[4][4];
    #pragma unroll
    for (int s = 0; s < 4; ++s)
        #pragma unroll
        for (int nt = 0; nt < 4; ++nt)
            acc[s][nt] = (f32x4){0.f, 0.f, 0.f, 0.f};

    const f16x2 z2 = (f16x2){ (_Float16)0.0f, (_Float16)0.0f };

    #pragma unroll
    for (int t = 0; t < 8; ++t) {
        const int kk = qk * 8 + 32 * t;
        // Wg slices from LDS (broadcast within 16-lane groups; conflict-free)
        union { f16x8 v; f16x2 p[4]; } w0u, w1u, bbu;
        w0u.v = *reinterpret_cast<const f16x8*>(&W0l[kk]);
        w1u.v = *reinterpret_cast<const f16x8*>(&W1l[kk]);
        bbu.v = *reinterpret_cast<const f16x8*>(&bgl[kk]);
        f16x8 bfrag[4];
        #pragma unroll
        for (int nt = 0; nt < 4; ++nt)
            bfrag[nt] = *reinterpret_cast<const f16x8*>(&Wl[(nt * 16 + m) * LDW + kk]);
        #pragma unroll
        for (int s = 0; s < 4; ++s) {
            union { f16x8 v; f16x2 p[4]; } af;
            #pragma unroll
            for (int j2 = 0; j2 < 4; ++j2) {
                f16x2 h = w0u.p[j2] * y0pk[s] + w1u.p[j2] * y1pk[s] + bbu.p[j2];
                af.p[j2] = __builtin_elementwise_max(h, z2);
            }
            #pragma unroll
            for (int nt = 0; nt < 4; ++nt)
                acc[s][nt] = __builtin_amdgcn_mfma_f32_16x16x32_f16(af.v, bfrag[nt], acc[s][nt], 0, 0, 0);
        }
    }

    // Epilogue: + b_proj, scalar stores (R9-verbatim — proven best)
    float bpf[4];
    #pragma unroll
    for (int nt = 0; nt < 4; ++nt) bpf[nt] = bp[c0 + nt * 16 + m];
    #pragma unroll
    for (int s = 0; s < 4; ++s) {
        #pragma unroll
        for (int nt = 0; nt < 4; ++nt) {
            const int e = c0 + nt * 16 + m;
            #pragma unroll
            for (int reg = 0; reg < 4; ++reg) {
                long r = rowbase + s * 16 + qk * 4 + reg;
                out[r * 256 + e] = acc[s][nt][reg] + bpf[nt];
            }
        }
    }
}

extern "C" void kernel_launch(void* const* d_in, const int* in_sizes, int n_in,
                              void* d_out, int out_size, void* d_ws, size_t ws_size,
                              hipStream_t stream) {
    const float* x  = (const float*)d_in[0];
    const float* Wg = (const float*)d_in[1];
    const float* bg = (const float*)d_in[2];
    const float* Wp = (const float*)d_in[3];
    const float* bp = (const float*)d_in[4];
    const int* ei   = (const int*)d_in[5];
    float* out = (float*)d_out;

    const int ne    = in_sizes[5] / 2;              // 84
    const int pairs = in_sizes[0] / (N_NODES * 2);  // 8192
    const int rows  = pairs * N_NODES;              // 835584

    int4*   gtu = (int4*)d_ws;                      // 102 int4
    float4* gtw = (float4*)((char*)d_ws + 2048);    // 102 float4

    build_tables<<<1, 128, 0, stream>>>(ei, ne, gtu, gtw);

    const int rowblocks = rows / 256;               // 3264
    gnn_main<<<dim3(rowblocks, 4), 256, 0, stream>>>(x, gtu, gtw, Wg, bg, Wp, bp, out);
}

// Round 15
// 199.486 us; speedup vs baseline: 1.8259x; 1.4516x over previous
//
#include <hip/hip_runtime.h>

#define N_NODES 102
#define NP 8192          // pairs (B*n)
#define RBLOCKS 3264     // 256-row blocks
#define RSTRIDE 128      // persistent grid x-dim

typedef _Float16 f16x8 __attribute__((ext_vector_type(8)));
typedef _Float16 f16x2 __attribute__((ext_vector_type(2)));
typedef float f32x4 __attribute__((ext_vector_type(4)));

// ---------------- Kernel 1: build sparse propagation tables ----------------------
__global__ void build_tables(const int* __restrict__ ei, int ne,
                             int4* __restrict__ gtu, float4* __restrict__ gtw) {
    __shared__ int   deg[N_NODES];
    __shared__ float dinv[N_NODES];
    __shared__ int   cnt[N_NODES];
    __shared__ int   tu[N_NODES][4];
    __shared__ float tw[N_NODES][4];
    int t = threadIdx.x;
    if (t < N_NODES) deg[t] = 1;                       // self-loop
    __syncthreads();
    if (t == 0) for (int e = 0; e < ne; ++e) deg[ei[ne + e]] += 1;
    __syncthreads();
    if (t < N_NODES) {
        dinv[t] = 1.0f / sqrtf((float)deg[t]);
        cnt[t] = 1;
        for (int j = 0; j < 4; ++j) { tu[t][j] = 2 * t; tw[t][j] = 0.0f; }
    }
    __syncthreads();
    if (t < N_NODES) tw[t][0] = dinv[t] * dinv[t];     // diagonal self-loop
    __syncthreads();
    if (t == 0) {
        for (int e = 0; e < ne; ++e) {
            int r = ei[e], c = ei[ne + e];
            int s = cnt[c] < 4 ? cnt[c] : 3;           // clamp (never hit here)
            cnt[c] = s + 1;
            tu[c][s] = 2 * r;
            tw[c][s] = dinv[r] * dinv[c];
        }
    }
    __syncthreads();
    if (t < N_NODES) {
        gtu[t] = make_int4(tu[t][0], tu[t][1], tu[t][2], tu[t][3]);
        gtw[t] = make_float4(tw[t][0], tw[t][1], tw[t][2], tw[t][3]);
    }
}

// ---------------- Kernel 1b: WpT[col][k] = (f16)Wp[k][col] (proven in R13) -------
__global__ void prep_w(const float* __restrict__ Wp, _Float16* __restrict__ WpT) {
    int tid = blockIdx.x * 256 + threadIdx.x;          // 64 x 256 = 16384
    for (int i = tid; i < 65536; i += 16384) {         // i = k*256 + col (coalesced)
        int col = i & 255, k = i >> 8;
        WpT[col * 256 + k] = (_Float16)Wp[i];
    }
}

// ---------------- Kernel 2: persistent fused GNN ---------------------------------
// 512 blocks (2/CU, zero tail). Block (rbi, cb): col-band cb fixed; B-operand
// fragments (64 cols x 256 k) hoisted into 128 VGPRs ONCE from WpT; then 26
// rowblocks of 256 rows each: {stage 3.3KB xs -> y-gen -> reg-fed MFMA t-loop ->
// scalar-store epilogue}. No per-rowblock weight staging, stores stream.
__global__ __launch_bounds__(256, 2) void gnn_main(
    const float* __restrict__ x,       // [NP][204] fp32
    const _Float16* __restrict__ WpT,  // [256 col][256 k] f16
    const int4*  __restrict__ gtu,     // [102]
    const float4* __restrict__ gtw,    // [102]
    const float* __restrict__ Wg,      // [2][256]
    const float* __restrict__ bg,      // [256]
    const float* __restrict__ bp,      // [256]
    float* __restrict__ out)           // [R][256]
{
    __shared__ float xs[4 * 2 * N_NODES];   // 3.3 KB
    __shared__ int4   stu[N_NODES];         // 1.6 KB
    __shared__ float4 stw[N_NODES];         // 1.6 KB
    __shared__ _Float16 W0l[256], W1l[256], bgl[256];  // 1.5 KB
    const int tid = threadIdx.x;
    const int w  = tid >> 6;
    const int l  = tid & 63;
    const int qk = l >> 4;
    const int m  = l & 15;
    const int c0  = blockIdx.y * 64;
    const int rbi = blockIdx.x;

    // Hoist all B fragments into registers (32 x 16B, L2-resident WpT)
    f16x8 bfragR[8][4];
    #pragma unroll
    for (int t = 0; t < 8; ++t)
        #pragma unroll
        for (int nt = 0; nt < 4; ++nt)
            bfragR[t][nt] = *reinterpret_cast<const f16x8*>(
                &WpT[(c0 + nt * 16 + m) * 256 + qk * 8 + 32 * t]);

    // Stage tables + GNN weights (once)
    if (tid < N_NODES) { stu[tid] = gtu[tid]; stw[tid] = gtw[tid]; }
    W0l[tid] = (_Float16)Wg[tid];
    W1l[tid] = (_Float16)Wg[256 + tid];
    bgl[tid] = (_Float16)bg[tid];

    float bpf[4];
    #pragma unroll
    for (int nt = 0; nt < 4; ++nt) bpf[nt] = bp[c0 + nt * 16 + m];

    const f16x2 z2 = (f16x2){ (_Float16)0.0f, (_Float16)0.0f };

    #pragma unroll 1
    for (int j = 0; j < 26; ++j) {
        const int rb = rbi + j * RSTRIDE;
        if (rb >= RBLOCKS) break;
        const int rowblk = rb * 256;
        const int pbase  = rowblk / N_NODES;

        __syncthreads();   // prior iteration's xs readers done
        #pragma unroll
        for (int pi = 0; pi < 4; ++pi) {
            int p = pbase + pi;
            if (tid < 2 * N_NODES)
                xs[pi * 2 * N_NODES + tid] = (p < NP) ? x[(size_t)p * (2 * N_NODES) + tid] : 0.0f;
        }
        __syncthreads();

        // y-gen from sparse tables (R9-verbatim)
        f16x2 y0pk[4], y1pk[4];
        #pragma unroll
        for (int s = 0; s < 4; ++s) {
            int r = rowblk + w * 64 + s * 16 + m;
            int p = r / N_NODES;
            int v = r - p * N_NODES;
            const float* xp = &xs[(p - pbase) * 2 * N_NODES];
            int4  U = stu[v];
            float4 W = stw[v];
            float a0 = W.x * xp[U.x]     + W.y * xp[U.y]
                     + W.z * xp[U.z]     + W.w * xp[U.w];
            float a1 = W.x * xp[U.x + 1] + W.y * xp[U.y + 1]
                     + W.z * xp[U.z + 1] + W.w * xp[U.w + 1];
            _Float16 h0 = (_Float16)a0;
            _Float16 h1 = (_Float16)a1;
            y0pk[s] = (f16x2){ h0, h0 };
            y1pk[s] = (f16x2){ h1, h1 };
        }

        f32x4 acc[4][4];
        #pragma unroll
        for (int s = 0; s < 4; ++s)
            #pragma unroll
            for (int nt = 0; nt < 4; ++nt)
                acc[s][nt] = (f32x4){0.f, 0.f, 0.f, 0.f};

        #pragma unroll
        for (int t = 0; t < 8; ++t) {
            const int kk = qk * 8 + 32 * t;
            union { f16x8 v; f16x2 p[4]; } w0u, w1u, bbu;
            w0u.v = *reinterpret_cast<const f16x8*>(&W0l[kk]);
            w1u.v = *reinterpret_cast<const f16x8*>(&W1l[kk]);
            bbu.v = *reinterpret_cast<const f16x8*>(&bgl[kk]);
            #pragma unroll
            for (int s = 0; s < 4; ++s) {
                union { f16x8 v; f16x2 p[4]; } af;
                #pragma unroll
                for (int j2 = 0; j2 < 4; ++j2) {
                    f16x2 h = w0u.p[j2] * y0pk[s] + w1u.p[j2] * y1pk[s] + bbu.p[j2];
                    af.p[j2] = __builtin_elementwise_max(h, z2);
                }
                #pragma unroll
                for (int nt = 0; nt < 4; ++nt)
                    acc[s][nt] = __builtin_amdgcn_mfma_f32_16x16x32_f16(af.v, bfragR[t][nt], acc[s][nt], 0, 0, 0);
            }
        }

        // Epilogue: + b_proj, scalar stores (R9-verbatim)
        const long rowbase = (long)rowblk + (long)w * 64;
        #pragma unroll
        for (int s = 0; s < 4; ++s) {
            #pragma unroll
            for (int nt = 0; nt < 4; ++nt) {
                const int e = c0 + nt * 16 + m;
                #pragma unroll
                for (int reg = 0; reg < 4; ++reg) {
                    long r = rowbase + s * 16 + qk * 4 + reg;
                    out[r * 256 + e] = acc[s][nt][reg] + bpf[nt];
                }
            }
        }
    }
}

extern "C" void kernel_launch(void* const* d_in, const int* in_sizes, int n_in,
                              void* d_out, int out_size, void* d_ws, size_t ws_size,
                              hipStream_t stream) {
    const float* x  = (const float*)d_in[0];
    const float* Wg = (const float*)d_in[1];
    const float* bg = (const float*)d_in[2];
    const float* Wp = (const float*)d_in[3];
    const float* bp = (const float*)d_in[4];
    const int* ei   = (const int*)d_in[5];
    float* out = (float*)d_out;

    const int ne = in_sizes[5] / 2;                 // 84

    int4*     gtu = (int4*)d_ws;                        // 102 int4
    float4*   gtw = (float4*)((char*)d_ws + 2048);      // 102 float4
    _Float16* WpT = (_Float16*)((char*)d_ws + 4096);    // 65536 f16 = 128 KB

    build_tables<<<1, 128, 0, stream>>>(ei, ne, gtu, gtw);
    prep_w<<<64, 256, 0, stream>>>(Wp, WpT);

    gnn_main<<<dim3(RSTRIDE, 4), 256, 0, stream>>>(x, WpT, gtu, gtw, Wg, bg, bp, out);
}